// Round 15
// baseline (108.371 us; speedup 1.0000x reference)
//
#include <hip/hip_runtime.h>
#include <hip/hip_bf16.h>

#define NCLASS 19
#define BINS 512
#define NB (NCLASS * BINS)  // 9728 bins
#define NREP 4
#define RPAD 8              // words; shifts each replica's bank phase by 8
#define RSTRIDE (NB + RPAD)
#define NSLICE 8            // fold slices (blocks per class in the tail)
#define IGNORE_IDX (-100)
#define HW_SHIFT 18  // 512*512 = 2^18 (fixed problem shape)
#define HW_C (1 << HW_SHIFT)

#define UNPACK(v)                                            \
  (((unsigned long long)((v) >> 16) << 32) |                 \
   (unsigned long long)((v) & 0xffffu))

// Load one 2-pixel set: 19 float2 logit streams + int2 labels.
#define LOADSET(V, LB, PIX)                                                  \
  {                                                                          \
    int n_ = (PIX) >> HW_SHIFT;                                              \
    int hw_ = (PIX) & (HW_C - 1);                                            \
    const float* lp_ =                                                       \
        logits + (((size_t)n_ * NCLASS) << HW_SHIFT) + hw_;                  \
    _Pragma("unroll") for (int c_ = 0; c_ < NCLASS; ++c_) {                  \
      float2 q_ = *(const float2*)(lp_ + ((size_t)c_ << HW_SHIFT));          \
      V[c_][0] = q_.x;                                                       \
      V[c_][1] = q_.y;                                                       \
    }                                                                        \
    LB = *(const int2*)(labels + (PIX));                                     \
  }

// Softmax + 2x19 histogram atomics for one 2-pixel set.
#define PROCSET(V, LB)                                                       \
  {                                                                          \
    float m0_ = -3.4e38f, m1_ = -3.4e38f;                                    \
    _Pragma("unroll") for (int c_ = 0; c_ < NCLASS; ++c_) {                  \
      m0_ = fmaxf(m0_, V[c_][0]);                                            \
      m1_ = fmaxf(m1_, V[c_][1]);                                            \
    }                                                                        \
    float s0_ = 0.f, s1_ = 0.f;                                              \
    _Pragma("unroll") for (int c_ = 0; c_ < NCLASS; ++c_) {                  \
      V[c_][0] = __expf(V[c_][0] - m0_); s0_ += V[c_][0];                    \
      V[c_][1] = __expf(V[c_][1] - m1_); s1_ += V[c_][1];                    \
    }                                                                        \
    float i0_ = 1.0f / s0_, i1_ = 1.0f / s1_;                                \
    int l0_ = LB.x, l1_ = LB.y;                                              \
    _Pragma("unroll") for (int c_ = 0; c_ < NCLASS; ++c_) {                  \
      if (l0_ != IGNORE_IDX) {                                               \
        float pr_ = V[c_][0] * i0_;                                          \
        bool pos_ = (c_ == l0_);                                             \
        float e_ = pos_ ? (1.0f - pr_) : pr_;                                \
        int b_ = min(BINS - 1, (int)(e_ * (float)BINS));                     \
        atomicAdd(&sh[rep + (c_ << 9) + b_], pos_ ? 0x10000u : 1u);          \
      }                                                                      \
      if (l1_ != IGNORE_IDX) {                                               \
        float pr_ = V[c_][1] * i1_;                                          \
        bool pos_ = (c_ == l1_);                                             \
        float e_ = pos_ ? (1.0f - pr_) : pr_;                                \
        int b_ = min(BINS - 1, (int)(e_ * (float)BINS));                     \
        atomicAdd(&sh[rep + (c_ << 9) + b_], pos_ ? 0x10000u : 1u);          \
      }                                                                      \
    }                                                                        \
  }

// ---------------------------------------------------------------------------
// Phase 1 (proven R11/R14 core, VERBATIM except counter zeroing now covers
// NCLASS+1 tickets): 2 px/thread float2 loads, 4-way lane-replicated LDS
// histogram (u32-packed pos<<16|neg), register double-buffer prefetch with
// named A/B sets. Kernel boundary makes the zeroed counters visible to the
// tail (deterministic, poison-safe, no extra memset dispatch).
// ---------------------------------------------------------------------------
__global__ void __launch_bounds__(1024, 4) hist_pf(
    const float* __restrict__ logits, const int* __restrict__ labels,
    unsigned* __restrict__ copies, unsigned* __restrict__ counters, int P,
    int ppb) {
  extern __shared__ unsigned sh[];  // NREP*RSTRIDE words ~= 152 KB
  if (blockIdx.x == 0 && threadIdx.x < NCLASS + 1) counters[threadIdx.x] = 0u;
  for (int i = threadIdx.x; i < NREP * RSTRIDE; i += 1024) sh[i] = 0u;
  __syncthreads();

  const int rep = (threadIdx.x & 3) * RSTRIDE;
  const int STEP = 1024 * 2;
  int p1 = min(P, blockIdx.x * ppb + ppb);
  int p = blockIdx.x * ppb + (int)threadIdx.x * 2;

  float va[NCLASS][2], vb[NCLASS][2];
  int2 la, lb;
  bool has = p < p1;
  if (has) LOADSET(va, la, p);
  while (has) {
    int pn = p + STEP;
    bool hasn = pn < p1;
    if (hasn) LOADSET(vb, lb, pn);  // prefetch next set
    PROCSET(va, la);
    p = pn;
    has = hasn;
    if (!has) break;
    pn = p + STEP;
    hasn = pn < p1;
    if (hasn) LOADSET(va, la, pn);  // prefetch next set
    PROCSET(vb, lb);
    p = pn;
    has = hasn;
  }
  __syncthreads();

  unsigned* dst = copies + (size_t)blockIdx.x * NB;
  for (int i = threadIdx.x; i < NB; i += 1024)
    dst[i] =
        sh[i] + sh[RSTRIDE + i] + sh[2 * RSTRIDE + i] + sh[3 * RSTRIDE + i];
}

// ---------------------------------------------------------------------------
// Phase 2: 19 classes x 8 slices = 152 blocks (8x the fold parallelism of
// R14's 19). Block (c,s) folds its 32 copies for class c (2 halves x 512
// bins, 4 independent accumulators) and writes a u64 slice to partS. Then
// the proven spin-free ticket (release fence + atomicAdd): the block that
// draws ticket NSLICE-1 — all 7 siblings provably done — combines the 8
// slices in FIXED order, runs the proven 512-wide Hillis-Steele suffix scan
// + Lovasz J (loss_c = (1/BINS)*sum_{b>=1} J_b, (CP,CN) inclusive suffix
// counts, nPos = suffix at bin 0), writes partial[c], and the 19th class
// finisher computes the fixed-order final mean. Deterministic: every sum is
// over fixed values in fixed index order regardless of ticket order.
// ---------------------------------------------------------------------------
__global__ void __launch_bounds__(1024) scan19_split(
    const unsigned* __restrict__ copies, unsigned long long* __restrict__ partS,
    float* __restrict__ partial, unsigned* __restrict__ counters,
    float* __restrict__ out, int R) {
  int c = blockIdx.x >> 3;
  int s = blockIdx.x & (NSLICE - 1);
  int tid = threadIdx.x;
  int bin = tid & (BINS - 1);
  int half = tid >> 9;  // 0 or 1

  __shared__ unsigned long long binsA[BINS];  // 4 KB (also scan array)
  __shared__ unsigned long long binsB[BINS];  // 4 KB
  __shared__ float fsum[16];
  __shared__ unsigned tk_sh;

  // ---- fold this slice's copies (R/8 of them; halves split them again) ----
  int spc = R >> 3;        // copies per slice (32 at R=256)
  int hc = spc >> 1;       // per half (16), multiple of 4 down to R=64
  int r0 = s * spc + half * hc;
  const unsigned* base = copies + (c << 9) + bin;
  unsigned long long a0 = 0, a1 = 0, a2 = 0, a3 = 0;
  for (int r = 0; r < hc; r += 4) {
    unsigned v0 = base[(size_t)(r0 + r + 0) * NB];
    unsigned v1 = base[(size_t)(r0 + r + 1) * NB];
    unsigned v2 = base[(size_t)(r0 + r + 2) * NB];
    unsigned v3 = base[(size_t)(r0 + r + 3) * NB];
    a0 += UNPACK(v0);
    a1 += UNPACK(v1);
    a2 += UNPACK(v2);
    a3 += UNPACK(v3);
  }
  unsigned long long a = (a0 + a1) + (a2 + a3);
  if (half == 0)
    binsA[bin] = a;
  else
    binsB[bin] = a;
  __syncthreads();
  if (half == 0) binsA[bin] += binsB[bin];
  __syncthreads();

  if (tid < BINS) partS[((size_t)blockIdx.x << 9) + tid] = binsA[tid];

  // ---- per-class ticket (spin-free, proven R13 pattern) ----
  __threadfence();  // release: partS slice visible before ticket
  __syncthreads();
  if (tid == 0) tk_sh = atomicAdd(&counters[c], 1u);
  __syncthreads();
  if (tk_sh != NSLICE - 1) return;  // 7 siblings exit; last one proceeds

  // ---- finisher: combine 8 slices in fixed order ----
  __threadfence();  // acquire
  if (tid < BINS) {
    unsigned long long t = 0;
#pragma unroll
    for (int i = 0; i < NSLICE; ++i)
      t += __hip_atomic_load(&partS[(((size_t)(c << 3) + i) << 9) + tid],
                             __ATOMIC_RELAXED, __HIP_MEMORY_SCOPE_AGENT);
    binsA[tid] = t;
  }
  __syncthreads();

  // ---- inclusive suffix scan over BINS entries (Hillis-Steele, 9 rounds) --
  for (int off = 1; off < BINS; off <<= 1) {
    unsigned long long add = 0;
    if (half == 0 && bin + off < BINS) add = binsA[bin + off];
    __syncthreads();
    if (half == 0) binsA[bin] += add;
    __syncthreads();
  }

  float nPos = (float)(unsigned)(binsA[0] >> 32);  // class total positives
  float acc = 0.f;
  if (half == 0 && bin >= 1) {
    unsigned long long suff = binsA[bin];
    float CP = (float)(unsigned)(suff >> 32);
    float CN = (float)(unsigned)(suff & 0xffffffffull);
    float uni = nPos + CN;
    if (uni > 0.f) acc = 1.0f - (nPos - CP) / uni;
  }

  // ---- block reduce (fixed order) + ticket-fused final mean ----
  for (int off = 32; off > 0; off >>= 1) acc += __shfl_down(acc, off, 64);
  int lane = tid & 63, w = tid >> 6;
  if (lane == 0) fsum[w] = acc;
  __syncthreads();
  if (tid == 0) {
    float t = 0.f;
#pragma unroll
    for (int i = 0; i < 16; ++i) t += fsum[i];
    partial[c] = t;
    __threadfence();  // release: partial[c] visible before final ticket
    unsigned tk = atomicAdd(&counters[NCLASS], 1u);
    if (tk == NCLASS - 1) {  // all 18 others already released their partial
      __threadfence();       // acquire
      float m = 0.f;
#pragma unroll
      for (int i = 0; i < NCLASS; ++i)
        m += __hip_atomic_load(&partial[i], __ATOMIC_RELAXED,
                               __HIP_MEMORY_SCOPE_AGENT);
      out[0] = m * (1.0f / ((float)BINS * (float)NCLASS));
    }
  }
}

extern "C" void kernel_launch(void* const* d_in, const int* in_sizes, int n_in,
                              void* d_out, int out_size, void* d_ws,
                              size_t ws_size, hipStream_t stream) {
  const float* logits = (const float*)d_in[0];
  const int* labels = (const int*)d_in[1];
  float* out = (float*)d_out;

  const int P = in_sizes[1];  // 8*512*512 = 2,097,152

  // R = copy count = hist grid; 256 = 1 block/CU. Shrink if ws is tiny
  // (R/16 stays a multiple of 4 down to R=64).
  int R = 256;
  while (R > 64 &&
         (size_t)R * NB * 4 + (size_t)NCLASS * NSLICE * BINS * 8 + 4096 >
             ws_size)
    R >>= 1;
  // ppb multiple of 2048 keeps float2/int2 loads aligned. 8192 at R=256.
  int ppb = ((P + R - 1) / R + 2047) & ~2047;

  char* ws = (char*)d_ws;
  unsigned* copies = (unsigned*)ws;
  unsigned long long* partS =
      (unsigned long long*)(ws + (size_t)R * NB * 4);
  float* partial = (float*)(partS + (size_t)NCLASS * NSLICE * BINS);
  unsigned* counters = (unsigned*)(partial + 32);

  size_t ldsBytes = (size_t)NREP * RSTRIDE * 4;  // ~152 KB -> 1 block/CU

  hist_pf<<<R, 1024, ldsBytes, stream>>>(logits, labels, copies, counters, P,
                                         ppb);
  scan19_split<<<NCLASS * NSLICE, 1024, 0, stream>>>(copies, partS, partial,
                                                     counters, out, R);
}

// Round 16
// 59.355 us; speedup vs baseline: 1.8258x; 1.8258x over previous
//
#include <hip/hip_runtime.h>
#include <hip/hip_bf16.h>

#define NCLASS 19
#define BINS 512
#define NB (NCLASS * BINS)  // 9728 bins
#define NREP 4
#define RPAD 8              // words; shifts each replica's bank phase by 8
#define RSTRIDE (NB + RPAD)
#define IGNORE_IDX (-100)
#define HW_SHIFT 18  // 512*512 = 2^18 (fixed problem shape)
#define HW_C (1 << HW_SHIFT)

#define UNPACK(v)                                            \
  (((unsigned long long)((v) >> 16) << 32) |                 \
   (unsigned long long)((v) & 0xffffu))

// Load one 2-pixel set: 19 float2 logit streams + int2 labels.
#define LOADSET(V, LB, PIX)                                                  \
  {                                                                          \
    int n_ = (PIX) >> HW_SHIFT;                                              \
    int hw_ = (PIX) & (HW_C - 1);                                            \
    const float* lp_ =                                                       \
        logits + (((size_t)n_ * NCLASS) << HW_SHIFT) + hw_;                  \
    _Pragma("unroll") for (int c_ = 0; c_ < NCLASS; ++c_) {                  \
      float2 q_ = *(const float2*)(lp_ + ((size_t)c_ << HW_SHIFT));          \
      V[c_][0] = q_.x;                                                       \
      V[c_][1] = q_.y;                                                       \
    }                                                                        \
    LB = *(const int2*)(labels + (PIX));                                     \
  }

// Softmax + 2x19 histogram atomics for one 2-pixel set.
#define PROCSET(V, LB)                                                       \
  {                                                                          \
    float m0_ = -3.4e38f, m1_ = -3.4e38f;                                    \
    _Pragma("unroll") for (int c_ = 0; c_ < NCLASS; ++c_) {                  \
      m0_ = fmaxf(m0_, V[c_][0]);                                            \
      m1_ = fmaxf(m1_, V[c_][1]);                                            \
    }                                                                        \
    float s0_ = 0.f, s1_ = 0.f;                                              \
    _Pragma("unroll") for (int c_ = 0; c_ < NCLASS; ++c_) {                  \
      V[c_][0] = __expf(V[c_][0] - m0_); s0_ += V[c_][0];                    \
      V[c_][1] = __expf(V[c_][1] - m1_); s1_ += V[c_][1];                    \
    }                                                                        \
    float i0_ = 1.0f / s0_, i1_ = 1.0f / s1_;                                \
    int l0_ = LB.x, l1_ = LB.y;                                              \
    _Pragma("unroll") for (int c_ = 0; c_ < NCLASS; ++c_) {                  \
      if (l0_ != IGNORE_IDX) {                                               \
        float pr_ = V[c_][0] * i0_;                                          \
        bool pos_ = (c_ == l0_);                                             \
        float e_ = pos_ ? (1.0f - pr_) : pr_;                                \
        int b_ = min(BINS - 1, (int)(e_ * (float)BINS));                     \
        atomicAdd(&sh[rep + (c_ << 9) + b_], pos_ ? 0x10000u : 1u);          \
      }                                                                      \
      if (l1_ != IGNORE_IDX) {                                               \
        float pr_ = V[c_][1] * i1_;                                          \
        bool pos_ = (c_ == l1_);                                             \
        float e_ = pos_ ? (1.0f - pr_) : pr_;                                \
        int b_ = min(BINS - 1, (int)(e_ * (float)BINS));                     \
        atomicAdd(&sh[rep + (c_ << 9) + b_], pos_ ? 0x10000u : 1u);          \
      }                                                                      \
    }                                                                        \
  }

// ---------------------------------------------------------------------------
// Phase 1 (proven R11/R14 core; only the FLUSH differs): 2 px/thread float2
// loads, 4-way lane-replicated LDS histogram (u32-packed pos<<16|neg),
// register double-buffer prefetch with named A/B sets. Flush: each block
// atomic-adds its 9728 block-total bins (u64-packed pos<<32|neg) directly
// into the global hist — 2.5M total atomics, lanes hit 64 DISTINCT
// consecutive addresses (no intra-wave conflict, unlike R1's disaster);
// worst per-cacheline serialization ~2048 RMWs, overlapped across blocks.
// This removes the 10 MB copies write + 10 MB tail re-read entirely.
// ---------------------------------------------------------------------------
__global__ void __launch_bounds__(1024, 4) hist_pf(
    const float* __restrict__ logits, const int* __restrict__ labels,
    unsigned long long* __restrict__ hist, int P, int ppb) {
  extern __shared__ unsigned sh[];  // NREP*RSTRIDE words ~= 152 KB
  for (int i = threadIdx.x; i < NREP * RSTRIDE; i += 1024) sh[i] = 0u;
  __syncthreads();

  const int rep = (threadIdx.x & 3) * RSTRIDE;
  const int STEP = 1024 * 2;
  int p1 = min(P, blockIdx.x * ppb + ppb);
  int p = blockIdx.x * ppb + (int)threadIdx.x * 2;

  float va[NCLASS][2], vb[NCLASS][2];
  int2 la, lb;
  bool has = p < p1;
  if (has) LOADSET(va, la, p);
  while (has) {
    int pn = p + STEP;
    bool hasn = pn < p1;
    if (hasn) LOADSET(vb, lb, pn);  // prefetch next set
    PROCSET(va, la);
    p = pn;
    has = hasn;
    if (!has) break;
    pn = p + STEP;
    hasn = pn < p1;
    if (hasn) LOADSET(va, la, pn);  // prefetch next set
    PROCSET(vb, lb);
    p = pn;
    has = hasn;
  }
  __syncthreads();

  for (int i = threadIdx.x; i < NB; i += 1024) {
    unsigned t =
        sh[i] + sh[RSTRIDE + i] + sh[2 * RSTRIDE + i] + sh[3 * RSTRIDE + i];
    atomicAdd(&hist[i], UNPACK(t));
  }
}

// ---------------------------------------------------------------------------
// Phase 2: 19 blocks x 512 threads. Reads the 78 KB global hist directly
// (LLC-resident), proven 512-wide Hillis-Steele inclusive suffix scan +
// Lovasz J: loss_c = (1/BINS)*sum_{b>=1} J_b, (CP,CN) inclusive suffix
// counts at b, nPos = suffix at bin 0 = class total. Final mean fused via
// the proven R13/R14 spin-free ticket (release fence + atomicAdd; the block
// drawing ticket NCLASS-1 sums partial[0..18] in fixed index order).
// ---------------------------------------------------------------------------
__global__ void __launch_bounds__(512) scan19_hist(
    const unsigned long long* __restrict__ hist, float* __restrict__ partial,
    unsigned* __restrict__ counter, float* __restrict__ out) {
  int c = blockIdx.x;
  __shared__ unsigned long long binsA[BINS];  // 4 KB
  __shared__ float fsum[8];
  int tid = threadIdx.x;

  binsA[tid] = hist[(c << 9) + tid];
  __syncthreads();

  // inclusive suffix scan over BINS entries (Hillis-Steele, 9 rounds)
  for (int off = 1; off < BINS; off <<= 1) {
    unsigned long long add = (tid + off < BINS) ? binsA[tid + off] : 0ull;
    __syncthreads();
    binsA[tid] += add;
    __syncthreads();
  }

  float nPos = (float)(unsigned)(binsA[0] >> 32);  // class total positives
  float acc = 0.f;
  if (tid >= 1) {
    unsigned long long suff = binsA[tid];
    float CP = (float)(unsigned)(suff >> 32);
    float CN = (float)(unsigned)(suff & 0xffffffffull);
    float uni = nPos + CN;
    if (uni > 0.f) acc = 1.0f - (nPos - CP) / uni;
  }

  // block reduce (fixed order) + ticket-fused final mean
  for (int off = 32; off > 0; off >>= 1) acc += __shfl_down(acc, off, 64);
  int lane = tid & 63, w = tid >> 6;
  if (lane == 0) fsum[w] = acc;
  __syncthreads();
  if (tid == 0) {
    float t = 0.f;
#pragma unroll
    for (int i = 0; i < 8; ++i) t += fsum[i];
    partial[c] = t;
    __threadfence();  // release: partial[c] visible before ticket
    unsigned tk = atomicAdd(counter, 1u);
    if (tk == NCLASS - 1) {  // all 18 others already released their partial
      __threadfence();       // acquire
      float m = 0.f;
#pragma unroll
      for (int i = 0; i < NCLASS; ++i)
        m += __hip_atomic_load(&partial[i], __ATOMIC_RELAXED,
                               __HIP_MEMORY_SCOPE_AGENT);
      out[0] = m * (1.0f / ((float)BINS * (float)NCLASS));
    }
  }
}

extern "C" void kernel_launch(void* const* d_in, const int* in_sizes, int n_in,
                              void* d_out, int out_size, void* d_ws,
                              size_t ws_size, hipStream_t stream) {
  const float* logits = (const float*)d_in[0];
  const int* labels = (const int*)d_in[1];
  float* out = (float*)d_out;

  const int P = in_sizes[1];  // 8*512*512 = 2,097,152

  const int R = 256;  // hist grid = 1 block/CU
  // ppb multiple of 2048 keeps float2/int2 loads aligned. 8192 at R=256.
  int ppb = ((P + R - 1) / R + 2047) & ~2047;

  char* ws = (char*)d_ws;
  unsigned long long* hist = (unsigned long long*)ws;   // NB u64 = 78 KB
  unsigned* counter = (unsigned*)(ws + (size_t)NB * 8); // zeroed with hist
  float* partial = (float*)(counter + 16);

  size_t ldsBytes = (size_t)NREP * RSTRIDE * 4;  // ~152 KB -> 1 block/CU

  // hist + ticket counter must be zero at the start of EVERY call (graph
  // replays do not re-poison): one small async memset, capture-safe.
  hipMemsetAsync(ws, 0, (size_t)NB * 8 + 64, stream);

  hist_pf<<<R, 1024, ldsBytes, stream>>>(logits, labels, hist, P, ppb);
  scan19_hist<<<NCLASS, 512, 0, stream>>>(hist, partial, counter, out);
}

// Round 17
// 50.314 us; speedup vs baseline: 2.1539x; 1.1797x over previous
//
#include <hip/hip_runtime.h>
#include <hip/hip_bf16.h>

#define NCLASS 19
#define BINS 512
#define NB (NCLASS * BINS)  // 9728 bins
#define NREP 4
#define RPAD 8              // words; shifts each replica's bank phase by 8
#define RSTRIDE (NB + RPAD)
#define SHARE 4             // hist blocks per shared copy (4*8192 < 65535)
#define IGNORE_IDX (-100)
#define HW_SHIFT 18  // 512*512 = 2^18 (fixed problem shape)
#define HW_C (1 << HW_SHIFT)

#define UNPACK(v)                                            \
  (((unsigned long long)((v) >> 16) << 32) |                 \
   (unsigned long long)((v) & 0xffffu))

// Load one 2-pixel set: 19 float2 logit streams + int2 labels.
#define LOADSET(V, LB, PIX)                                                  \
  {                                                                          \
    int n_ = (PIX) >> HW_SHIFT;                                              \
    int hw_ = (PIX) & (HW_C - 1);                                            \
    const float* lp_ =                                                       \
        logits + (((size_t)n_ * NCLASS) << HW_SHIFT) + hw_;                  \
    _Pragma("unroll") for (int c_ = 0; c_ < NCLASS; ++c_) {                  \
      float2 q_ = *(const float2*)(lp_ + ((size_t)c_ << HW_SHIFT));          \
      V[c_][0] = q_.x;                                                       \
      V[c_][1] = q_.y;                                                       \
    }                                                                        \
    LB = *(const int2*)(labels + (PIX));                                     \
  }

// Softmax + 2x19 histogram atomics for one 2-pixel set.
#define PROCSET(V, LB)                                                       \
  {                                                                          \
    float m0_ = -3.4e38f, m1_ = -3.4e38f;                                    \
    _Pragma("unroll") for (int c_ = 0; c_ < NCLASS; ++c_) {                  \
      m0_ = fmaxf(m0_, V[c_][0]);                                            \
      m1_ = fmaxf(m1_, V[c_][1]);                                            \
    }                                                                        \
    float s0_ = 0.f, s1_ = 0.f;                                              \
    _Pragma("unroll") for (int c_ = 0; c_ < NCLASS; ++c_) {                  \
      V[c_][0] = __expf(V[c_][0] - m0_); s0_ += V[c_][0];                    \
      V[c_][1] = __expf(V[c_][1] - m1_); s1_ += V[c_][1];                    \
    }                                                                        \
    float i0_ = 1.0f / s0_, i1_ = 1.0f / s1_;                                \
    int l0_ = LB.x, l1_ = LB.y;                                              \
    _Pragma("unroll") for (int c_ = 0; c_ < NCLASS; ++c_) {                  \
      if (l0_ != IGNORE_IDX) {                                               \
        float pr_ = V[c_][0] * i0_;                                          \
        bool pos_ = (c_ == l0_);                                             \
        float e_ = pos_ ? (1.0f - pr_) : pr_;                                \
        int b_ = min(BINS - 1, (int)(e_ * (float)BINS));                     \
        atomicAdd(&sh[rep + (c_ << 9) + b_], pos_ ? 0x10000u : 1u);          \
      }                                                                      \
      if (l1_ != IGNORE_IDX) {                                               \
        float pr_ = V[c_][1] * i1_;                                          \
        bool pos_ = (c_ == l1_);                                             \
        float e_ = pos_ ? (1.0f - pr_) : pr_;                                \
        int b_ = min(BINS - 1, (int)(e_ * (float)BINS));                     \
        atomicAdd(&sh[rep + (c_ << 9) + b_], pos_ ? 0x10000u : 1u);          \
      }                                                                      \
    }                                                                        \
  }

// ---------------------------------------------------------------------------
// Phase 1 (proven R11/R14 core; only the FLUSH differs): 2 px/thread float2
// loads, 4-way lane-replicated LDS histogram (u32-packed pos<<16|neg),
// register double-buffer prefetch with named A/B sets. Flush: groups of
// SHARE=4 blocks atomic-add their u32 block-totals into one shared copy —
// contention is exactly 4 RMWs/address (R16's pathology was 256-way), and
// the tail's read shrinks 10 MB -> 2.5 MB. Per-bin field max 4*8192 = 32768
// < 65535, provably no u16 overflow. Block 0 zeroes the scan ticket counter
// (kernel boundary publishes it — proven R14 pattern).
// ---------------------------------------------------------------------------
__global__ void __launch_bounds__(1024, 4) hist_pf(
    const float* __restrict__ logits, const int* __restrict__ labels,
    unsigned* __restrict__ copies, unsigned* __restrict__ counter, int P,
    int ppb) {
  extern __shared__ unsigned sh[];  // NREP*RSTRIDE words ~= 152 KB
  if (blockIdx.x == 0 && threadIdx.x == 0) *counter = 0u;
  for (int i = threadIdx.x; i < NREP * RSTRIDE; i += 1024) sh[i] = 0u;
  __syncthreads();

  const int rep = (threadIdx.x & 3) * RSTRIDE;
  const int STEP = 1024 * 2;
  int p1 = min(P, blockIdx.x * ppb + ppb);
  int p = blockIdx.x * ppb + (int)threadIdx.x * 2;

  float va[NCLASS][2], vb[NCLASS][2];
  int2 la, lb;
  bool has = p < p1;
  if (has) LOADSET(va, la, p);
  while (has) {
    int pn = p + STEP;
    bool hasn = pn < p1;
    if (hasn) LOADSET(vb, lb, pn);  // prefetch next set
    PROCSET(va, la);
    p = pn;
    has = hasn;
    if (!has) break;
    pn = p + STEP;
    hasn = pn < p1;
    if (hasn) LOADSET(va, la, pn);  // prefetch next set
    PROCSET(vb, lb);
    p = pn;
    has = hasn;
  }
  __syncthreads();

  unsigned* dst = copies + (size_t)(blockIdx.x >> 2) * NB;
  for (int i = threadIdx.x; i < NB; i += 1024) {
    unsigned t =
        sh[i] + sh[RSTRIDE + i] + sh[2 * RSTRIDE + i] + sh[3 * RSTRIDE + i];
    atomicAdd(&dst[i], t);
  }
}

// ---------------------------------------------------------------------------
// Phase 2 (fused tail, proven R14 shape at RC=64 copies): one block per
// class, 1024 threads = 2 halves x 512 bins; each thread folds RC/2 copies
// with 8 INDEPENDENT accumulators (4 dependent rounds), halves combined via
// LDS. Then the 512-wide Hillis-Steele inclusive suffix scan and Lovasz J:
// loss_c = (1/BINS)*sum_{b>=1} J_b, (CP,CN) inclusive suffix counts at b;
// nPos = suffix at bin 0. Final mean fused via the proven spin-free ticket.
// ---------------------------------------------------------------------------
__global__ void __launch_bounds__(1024) scan19_fused(
    const unsigned* __restrict__ copies, float* __restrict__ partial,
    unsigned* __restrict__ counter, float* __restrict__ out, int RC) {
  int c = blockIdx.x;
  __shared__ unsigned long long binsA[BINS];  // 4 KB (also scan array)
  __shared__ unsigned long long binsB[BINS];  // 4 KB
  __shared__ float fsum[16];
  int tid = threadIdx.x;
  int bin = tid & (BINS - 1);
  int half = tid >> 9;  // 0 or 1

  // ---- fold: each thread sums RC/2 copies for its bin, 8-way ILP ----
  int hc = RC >> 1;  // copies per half (32 at RC=64), multiple of 8
  int r0 = half * hc;
  const unsigned* base = copies + (c << 9) + bin;
  unsigned long long a0 = 0, a1 = 0, a2 = 0, a3 = 0, a4 = 0, a5 = 0, a6 = 0,
                     a7 = 0;
  for (int r = 0; r < hc; r += 8) {
    unsigned v0 = base[(size_t)(r0 + r + 0) * NB];
    unsigned v1 = base[(size_t)(r0 + r + 1) * NB];
    unsigned v2 = base[(size_t)(r0 + r + 2) * NB];
    unsigned v3 = base[(size_t)(r0 + r + 3) * NB];
    unsigned v4 = base[(size_t)(r0 + r + 4) * NB];
    unsigned v5 = base[(size_t)(r0 + r + 5) * NB];
    unsigned v6 = base[(size_t)(r0 + r + 6) * NB];
    unsigned v7 = base[(size_t)(r0 + r + 7) * NB];
    a0 += UNPACK(v0);
    a1 += UNPACK(v1);
    a2 += UNPACK(v2);
    a3 += UNPACK(v3);
    a4 += UNPACK(v4);
    a5 += UNPACK(v5);
    a6 += UNPACK(v6);
    a7 += UNPACK(v7);
  }
  unsigned long long a = ((a0 + a1) + (a2 + a3)) + ((a4 + a5) + (a6 + a7));
  if (half == 0)
    binsA[bin] = a;
  else
    binsB[bin] = a;
  __syncthreads();
  if (half == 0) binsA[bin] += binsB[bin];
  __syncthreads();

  // ---- inclusive suffix scan over BINS entries (Hillis-Steele, 9 rounds) --
  for (int off = 1; off < BINS; off <<= 1) {
    unsigned long long add = 0;
    if (half == 0 && bin + off < BINS) add = binsA[bin + off];
    __syncthreads();
    if (half == 0) binsA[bin] += add;
    __syncthreads();
  }

  float nPos = (float)(unsigned)(binsA[0] >> 32);  // class total positives
  float acc = 0.f;
  if (half == 0 && bin >= 1) {
    unsigned long long suff = binsA[bin];
    float CP = (float)(unsigned)(suff >> 32);
    float CN = (float)(unsigned)(suff & 0xffffffffull);
    float uni = nPos + CN;
    if (uni > 0.f) acc = 1.0f - (nPos - CP) / uni;
  }

  // ---- block reduce (fixed order) + ticket-fused final mean ----
  for (int off = 32; off > 0; off >>= 1) acc += __shfl_down(acc, off, 64);
  int lane = tid & 63, w = tid >> 6;
  if (lane == 0) fsum[w] = acc;
  __syncthreads();
  if (tid == 0) {
    float t = 0.f;
#pragma unroll
    for (int i = 0; i < 16; ++i) t += fsum[i];
    partial[c] = t;
    __threadfence();  // release: partial[c] visible before ticket
    unsigned tk = atomicAdd(counter, 1u);
    if (tk == NCLASS - 1) {  // all 18 others already released their partial
      __threadfence();       // acquire
      float m = 0.f;
#pragma unroll
      for (int i = 0; i < NCLASS; ++i)
        m += __hip_atomic_load(&partial[i], __ATOMIC_RELAXED,
                               __HIP_MEMORY_SCOPE_AGENT);
      out[0] = m * (1.0f / ((float)BINS * (float)NCLASS));
    }
  }
}

extern "C" void kernel_launch(void* const* d_in, const int* in_sizes, int n_in,
                              void* d_out, int out_size, void* d_ws,
                              size_t ws_size, hipStream_t stream) {
  const float* logits = (const float*)d_in[0];
  const int* labels = (const int*)d_in[1];
  float* out = (float*)d_out;

  const int P = in_sizes[1];  // 8*512*512 = 2,097,152

  const int R = 256;          // hist grid = 1 block/CU
  const int RC = R / SHARE;   // shared copies (64)
  // ppb multiple of 2048 keeps float2/int2 loads aligned. 8192 at R=256.
  int ppb = ((P + R - 1) / R + 2047) & ~2047;

  char* ws = (char*)d_ws;
  unsigned* copies = (unsigned*)ws;                       // RC*NB*4 = 2.5 MB
  float* partial = (float*)(ws + (size_t)RC * NB * 4);
  unsigned* counter = (unsigned*)(partial + 32);

  size_t ldsBytes = (size_t)NREP * RSTRIDE * 4;  // ~152 KB -> 1 block/CU

  // Shared copies must be zero at the start of EVERY call (4 blocks
  // atomic-add into each; graph replays do not re-poison).
  hipMemsetAsync(copies, 0, (size_t)RC * NB * 4, stream);

  hist_pf<<<R, 1024, ldsBytes, stream>>>(logits, labels, copies, counter, P,
                                         ppb);
  scan19_fused<<<NCLASS, 1024, 0, stream>>>(copies, partial, counter, out, RC);
}

// Round 18
// 45.386 us; speedup vs baseline: 2.3877x; 1.1086x over previous
//
#include <hip/hip_runtime.h>
#include <hip/hip_bf16.h>

#define NCLASS 19
#define BINS 512
#define NB (NCLASS * BINS)  // 9728 bins
#define NREP 4
#define RPAD 8              // words; shifts each replica's bank phase by 8
#define RSTRIDE (NB + RPAD)
#define IGNORE_IDX (-100)
#define HW_SHIFT 18  // 512*512 = 2^18 (fixed problem shape)
#define HW_C (1 << HW_SHIFT)

#define UNPACK(v)                                            \
  (((unsigned long long)((v) >> 16) << 32) |                 \
   (unsigned long long)((v) & 0xffffu))

// Load one 2-pixel set: 19 float2 logit streams + int2 labels.
#define LOADSET(V, LB, PIX)                                                  \
  {                                                                          \
    int n_ = (PIX) >> HW_SHIFT;                                              \
    int hw_ = (PIX) & (HW_C - 1);                                            \
    const float* lp_ =                                                       \
        logits + (((size_t)n_ * NCLASS) << HW_SHIFT) + hw_;                  \
    _Pragma("unroll") for (int c_ = 0; c_ < NCLASS; ++c_) {                  \
      float2 q_ = *(const float2*)(lp_ + ((size_t)c_ << HW_SHIFT));          \
      V[c_][0] = q_.x;                                                       \
      V[c_][1] = q_.y;                                                       \
    }                                                                        \
    LB = *(const int2*)(labels + (PIX));                                     \
  }

// Softmax + 2x19 histogram atomics for one 2-pixel set.
#define PROCSET(V, LB)                                                       \
  {                                                                          \
    float m0_ = -3.4e38f, m1_ = -3.4e38f;                                    \
    _Pragma("unroll") for (int c_ = 0; c_ < NCLASS; ++c_) {                  \
      m0_ = fmaxf(m0_, V[c_][0]);                                            \
      m1_ = fmaxf(m1_, V[c_][1]);                                            \
    }                                                                        \
    float s0_ = 0.f, s1_ = 0.f;                                              \
    _Pragma("unroll") for (int c_ = 0; c_ < NCLASS; ++c_) {                  \
      V[c_][0] = __expf(V[c_][0] - m0_); s0_ += V[c_][0];                    \
      V[c_][1] = __expf(V[c_][1] - m1_); s1_ += V[c_][1];                    \
    }                                                                        \
    float i0_ = 1.0f / s0_, i1_ = 1.0f / s1_;                                \
    int l0_ = LB.x, l1_ = LB.y;                                              \
    _Pragma("unroll") for (int c_ = 0; c_ < NCLASS; ++c_) {                  \
      if (l0_ != IGNORE_IDX) {                                               \
        float pr_ = V[c_][0] * i0_;                                          \
        bool pos_ = (c_ == l0_);                                             \
        float e_ = pos_ ? (1.0f - pr_) : pr_;                                \
        int b_ = min(BINS - 1, (int)(e_ * (float)BINS));                     \
        atomicAdd(&sh[rep + (c_ << 9) + b_], pos_ ? 0x10000u : 1u);          \
      }                                                                      \
      if (l1_ != IGNORE_IDX) {                                               \
        float pr_ = V[c_][1] * i1_;                                          \
        bool pos_ = (c_ == l1_);                                             \
        float e_ = pos_ ? (1.0f - pr_) : pr_;                                \
        int b_ = min(BINS - 1, (int)(e_ * (float)BINS));                     \
        atomicAdd(&sh[rep + (c_ << 9) + b_], pos_ ? 0x10000u : 1u);          \
      }                                                                      \
    }                                                                        \
  }

// ---------------------------------------------------------------------------
// Phase 1 (proven R14 core, VERBATIM): 2 px/thread float2 loads, 4-way
// lane-replicated LDS histogram (u32-packed pos<<16|neg), register
// double-buffer prefetch with named A/B sets, plain-store flush of the
// block-total copy. Zeroes the scan ticket counter (kernel boundary
// publishes it — proven pattern, no extra memset dispatch).
// ---------------------------------------------------------------------------
__global__ void __launch_bounds__(1024, 4) hist_pf(
    const float* __restrict__ logits, const int* __restrict__ labels,
    unsigned* __restrict__ copies, unsigned* __restrict__ counter, int P,
    int ppb) {
  extern __shared__ unsigned sh[];  // NREP*RSTRIDE words ~= 152 KB
  if (blockIdx.x == 0 && threadIdx.x == 0) *counter = 0u;
  for (int i = threadIdx.x; i < NREP * RSTRIDE; i += 1024) sh[i] = 0u;
  __syncthreads();

  const int rep = (threadIdx.x & 3) * RSTRIDE;
  const int STEP = 1024 * 2;
  int p1 = min(P, blockIdx.x * ppb + ppb);
  int p = blockIdx.x * ppb + (int)threadIdx.x * 2;

  float va[NCLASS][2], vb[NCLASS][2];
  int2 la, lb;
  bool has = p < p1;
  if (has) LOADSET(va, la, p);
  while (has) {
    int pn = p + STEP;
    bool hasn = pn < p1;
    if (hasn) LOADSET(vb, lb, pn);  // prefetch next set
    PROCSET(va, la);
    p = pn;
    has = hasn;
    if (!has) break;
    pn = p + STEP;
    hasn = pn < p1;
    if (hasn) LOADSET(va, la, pn);  // prefetch next set
    PROCSET(vb, lb);
    p = pn;
    has = hasn;
  }
  __syncthreads();

  unsigned* dst = copies + (size_t)blockIdx.x * NB;
  for (int i = threadIdx.x; i < NB; i += 1024)
    dst[i] =
        sh[i] + sh[RSTRIDE + i] + sh[2 * RSTRIDE + i] + sh[3 * RSTRIDE + i];
}

// ---------------------------------------------------------------------------
// Phase 2: wide fold. 76 blocks x 1024 threads = 128 bins/block x 8 slices.
// Thread (s, bl) folds copies r==s (mod 8) for global bin blockIdx*128+bl
// with 8 INDEPENDENT loads per round (4 rounds at R=256) -> ~2.4 MB in
// flight device-wide, 10 MB read at ~4 TB/s. Slices combine via LDS; the
// 78 KB u64 hist is written with plain coalesced stores. No atomics.
// ---------------------------------------------------------------------------
__global__ void __launch_bounds__(1024) fold76(
    const unsigned* __restrict__ copies, unsigned long long* __restrict__ hist,
    int R) {
  __shared__ unsigned long long sl[8][128];  // 8 KB
  int tid = threadIdx.x;
  int bl = tid & 127;  // bin within this block's chunk
  int s = tid >> 7;    // slice 0..7
  int gbin = blockIdx.x * 128 + bl;
  const unsigned* base = copies + gbin;

  unsigned long long a0 = 0, a1 = 0, a2 = 0, a3 = 0, a4 = 0, a5 = 0, a6 = 0,
                     a7 = 0;
  for (int r = s; r < R; r += 64) {  // 8 slices x 8 ILP = stride 64
    unsigned v0 = base[(size_t)(r + 0) * NB];
    unsigned v1 = base[(size_t)(r + 8) * NB];
    unsigned v2 = base[(size_t)(r + 16) * NB];
    unsigned v3 = base[(size_t)(r + 24) * NB];
    unsigned v4 = base[(size_t)(r + 32) * NB];
    unsigned v5 = base[(size_t)(r + 40) * NB];
    unsigned v6 = base[(size_t)(r + 48) * NB];
    unsigned v7 = base[(size_t)(r + 56) * NB];
    a0 += UNPACK(v0);
    a1 += UNPACK(v1);
    a2 += UNPACK(v2);
    a3 += UNPACK(v3);
    a4 += UNPACK(v4);
    a5 += UNPACK(v5);
    a6 += UNPACK(v6);
    a7 += UNPACK(v7);
  }
  sl[s][bl] = ((a0 + a1) + (a2 + a3)) + ((a4 + a5) + (a6 + a7));
  __syncthreads();

  if (tid < 128) {
    unsigned long long t = 0;
#pragma unroll
    for (int i = 0; i < 8; ++i) t += sl[i][tid];
    hist[gbin] = t;
  }
}

// ---------------------------------------------------------------------------
// Phase 3 (R16's proven scan half — its regression was hist-side): 19 blocks
// x 512 threads read the L2-resident 78 KB u64 hist, run the 512-wide
// Hillis-Steele inclusive suffix scan + Lovasz J (loss_c = (1/BINS) *
// sum_{b>=1} J_b, (CP,CN) inclusive suffix counts at b, nPos = suffix at
// bin 0), and fuse the final mean via the proven spin-free ticket.
// ---------------------------------------------------------------------------
__global__ void __launch_bounds__(512) scan19_hist(
    const unsigned long long* __restrict__ hist, float* __restrict__ partial,
    unsigned* __restrict__ counter, float* __restrict__ out) {
  int c = blockIdx.x;
  __shared__ unsigned long long binsA[BINS];  // 4 KB
  __shared__ float fsum[8];
  int tid = threadIdx.x;

  binsA[tid] = hist[(c << 9) + tid];
  __syncthreads();

  // inclusive suffix scan over BINS entries (Hillis-Steele, 9 rounds)
  for (int off = 1; off < BINS; off <<= 1) {
    unsigned long long add = (tid + off < BINS) ? binsA[tid + off] : 0ull;
    __syncthreads();
    binsA[tid] += add;
    __syncthreads();
  }

  float nPos = (float)(unsigned)(binsA[0] >> 32);  // class total positives
  float acc = 0.f;
  if (tid >= 1) {
    unsigned long long suff = binsA[tid];
    float CP = (float)(unsigned)(suff >> 32);
    float CN = (float)(unsigned)(suff & 0xffffffffull);
    float uni = nPos + CN;
    if (uni > 0.f) acc = 1.0f - (nPos - CP) / uni;
  }

  // block reduce (fixed order) + ticket-fused final mean
  for (int off = 32; off > 0; off >>= 1) acc += __shfl_down(acc, off, 64);
  int lane = tid & 63, w = tid >> 6;
  if (lane == 0) fsum[w] = acc;
  __syncthreads();
  if (tid == 0) {
    float t = 0.f;
#pragma unroll
    for (int i = 0; i < 8; ++i) t += fsum[i];
    partial[c] = t;
    __threadfence();  // release: partial[c] visible before ticket
    unsigned tk = atomicAdd(counter, 1u);
    if (tk == NCLASS - 1) {  // all 18 others already released their partial
      __threadfence();       // acquire
      float m = 0.f;
#pragma unroll
      for (int i = 0; i < NCLASS; ++i)
        m += __hip_atomic_load(&partial[i], __ATOMIC_RELAXED,
                               __HIP_MEMORY_SCOPE_AGENT);
      out[0] = m * (1.0f / ((float)BINS * (float)NCLASS));
    }
  }
}

extern "C" void kernel_launch(void* const* d_in, const int* in_sizes, int n_in,
                              void* d_out, int out_size, void* d_ws,
                              size_t ws_size, hipStream_t stream) {
  const float* logits = (const float*)d_in[0];
  const int* labels = (const int*)d_in[1];
  float* out = (float*)d_out;

  const int P = in_sizes[1];  // 8*512*512 = 2,097,152

  // R = copy count = hist grid; 256 = 1 block/CU. Shrink if ws is tiny
  // (R stays a multiple of 64 for fold76's slice/ILP stride).
  int R = 256;
  while (R > 64 && (size_t)R * NB * 4 + (size_t)NB * 8 + 4096 > ws_size)
    R >>= 1;
  // ppb multiple of 2048 keeps float2/int2 loads aligned. 8192 at R=256.
  int ppb = ((P + R - 1) / R + 2047) & ~2047;

  char* ws = (char*)d_ws;
  unsigned* copies = (unsigned*)ws;                            // 10 MB
  unsigned long long* hist =
      (unsigned long long*)(ws + (size_t)R * NB * 4);          // 78 KB
  float* partial = (float*)(hist + NB);
  unsigned* counter = (unsigned*)(partial + 32);

  size_t ldsBytes = (size_t)NREP * RSTRIDE * 4;  // ~152 KB -> 1 block/CU

  hist_pf<<<R, 1024, ldsBytes, stream>>>(logits, labels, copies, counter, P,
                                         ppb);
  fold76<<<NB / 128, 1024, 0, stream>>>(copies, hist, R);
  scan19_hist<<<NCLASS, 512, 0, stream>>>(hist, partial, counter, out);
}

// Round 19
// 45.236 us; speedup vs baseline: 2.3957x; 1.0033x over previous
//
#include <hip/hip_runtime.h>
#include <hip/hip_bf16.h>

#define NCLASS 19
#define BINS 512
#define NB (NCLASS * BINS)  // 9728 bins
#define NREP 4
#define RPAD 8              // words; shifts each replica's bank phase by 8
#define RSTRIDE (NB + RPAD)
#define IGNORE_IDX (-100)
#define HW_SHIFT 18  // 512*512 = 2^18 (fixed problem shape)
#define HW_C (1 << HW_SHIFT)

#define UNPACK(v)                                            \
  (((unsigned long long)((v) >> 16) << 32) |                 \
   (unsigned long long)((v) & 0xffffu))

// Load one 2-pixel set: 19 float2 logit streams + int2 labels.
#define LOADSET(V, LB, PIX)                                                  \
  {                                                                          \
    int n_ = (PIX) >> HW_SHIFT;                                              \
    int hw_ = (PIX) & (HW_C - 1);                                            \
    const float* lp_ =                                                       \
        logits + (((size_t)n_ * NCLASS) << HW_SHIFT) + hw_;                  \
    _Pragma("unroll") for (int c_ = 0; c_ < NCLASS; ++c_) {                  \
      float2 q_ = *(const float2*)(lp_ + ((size_t)c_ << HW_SHIFT));          \
      V[c_][0] = q_.x;                                                       \
      V[c_][1] = q_.y;                                                       \
    }                                                                        \
    LB = *(const int2*)(labels + (PIX));                                     \
  }

// Softmax + 2x19 histogram atomics for one 2-pixel set.
#define PROCSET(V, LB)                                                       \
  {                                                                          \
    float m0_ = -3.4e38f, m1_ = -3.4e38f;                                    \
    _Pragma("unroll") for (int c_ = 0; c_ < NCLASS; ++c_) {                  \
      m0_ = fmaxf(m0_, V[c_][0]);                                            \
      m1_ = fmaxf(m1_, V[c_][1]);                                            \
    }                                                                        \
    float s0_ = 0.f, s1_ = 0.f;                                              \
    _Pragma("unroll") for (int c_ = 0; c_ < NCLASS; ++c_) {                  \
      V[c_][0] = __expf(V[c_][0] - m0_); s0_ += V[c_][0];                    \
      V[c_][1] = __expf(V[c_][1] - m1_); s1_ += V[c_][1];                    \
    }                                                                        \
    float i0_ = 1.0f / s0_, i1_ = 1.0f / s1_;                                \
    int l0_ = LB.x, l1_ = LB.y;                                              \
    _Pragma("unroll") for (int c_ = 0; c_ < NCLASS; ++c_) {                  \
      if (l0_ != IGNORE_IDX) {                                               \
        float pr_ = V[c_][0] * i0_;                                          \
        bool pos_ = (c_ == l0_);                                             \
        float e_ = pos_ ? (1.0f - pr_) : pr_;                                \
        int b_ = min(BINS - 1, (int)(e_ * (float)BINS));                     \
        atomicAdd(&sh[rep + (c_ << 9) + b_], pos_ ? 0x10000u : 1u);          \
      }                                                                      \
      if (l1_ != IGNORE_IDX) {                                               \
        float pr_ = V[c_][1] * i1_;                                          \
        bool pos_ = (c_ == l1_);                                             \
        float e_ = pos_ ? (1.0f - pr_) : pr_;                                \
        int b_ = min(BINS - 1, (int)(e_ * (float)BINS));                     \
        atomicAdd(&sh[rep + (c_ << 9) + b_], pos_ ? 0x10000u : 1u);          \
      }                                                                      \
    }                                                                        \
  }

// ---------------------------------------------------------------------------
// Phase 1 (proven R14/R18 core, VERBATIM): 2 px/thread float2 loads, 4-way
// lane-replicated LDS histogram (u32-packed pos<<16|neg), register
// double-buffer prefetch with named A/B sets, plain-store flush of the
// block-total copy. Zeroes the scan ticket counter (kernel boundary
// publishes it — proven pattern, no extra memset dispatch).
// ---------------------------------------------------------------------------
__global__ void __launch_bounds__(1024, 4) hist_pf(
    const float* __restrict__ logits, const int* __restrict__ labels,
    unsigned* __restrict__ copies, unsigned* __restrict__ counter, int P,
    int ppb) {
  extern __shared__ unsigned sh[];  // NREP*RSTRIDE words ~= 152 KB
  if (blockIdx.x == 0 && threadIdx.x == 0) *counter = 0u;
  for (int i = threadIdx.x; i < NREP * RSTRIDE; i += 1024) sh[i] = 0u;
  __syncthreads();

  const int rep = (threadIdx.x & 3) * RSTRIDE;
  const int STEP = 1024 * 2;
  int p1 = min(P, blockIdx.x * ppb + ppb);
  int p = blockIdx.x * ppb + (int)threadIdx.x * 2;

  float va[NCLASS][2], vb[NCLASS][2];
  int2 la, lb;
  bool has = p < p1;
  if (has) LOADSET(va, la, p);
  while (has) {
    int pn = p + STEP;
    bool hasn = pn < p1;
    if (hasn) LOADSET(vb, lb, pn);  // prefetch next set
    PROCSET(va, la);
    p = pn;
    has = hasn;
    if (!has) break;
    pn = p + STEP;
    hasn = pn < p1;
    if (hasn) LOADSET(va, la, pn);  // prefetch next set
    PROCSET(vb, lb);
    p = pn;
    has = hasn;
  }
  __syncthreads();

  unsigned* dst = copies + (size_t)blockIdx.x * NB;
  for (int i = threadIdx.x; i < NB; i += 1024)
    dst[i] =
        sh[i] + sh[RSTRIDE + i] + sh[2 * RSTRIDE + i] + sh[3 * RSTRIDE + i];
}

// ---------------------------------------------------------------------------
// Phase 2: BW-bound fold. 152 blocks = 2 copy-halves x 76 bin-chunks, 1024
// threads = 32 subslices x 32 quads. Thread (s,q) folds its half's copies
// r = rhalf*128 + s + 32k for bins [4q..4q+3] of its chunk, via uint4 loads
// (16 B/lane, 1 KB/wave/instruction). In-flight ~4.9 MB device-wide -> the
// 10 MB read runs at HBM rate (~1.7 us). Subslices combine via LDS; writes
// part[2][NB] u64 (156 KB, L2-resident) with plain coalesced stores.
// ---------------------------------------------------------------------------
__global__ void __launch_bounds__(1024) fold_wide(
    const unsigned* __restrict__ copies, unsigned long long* __restrict__ part,
    int R) {
  const int NCHUNK = NB / 128;  // 76
  int rhalf = blockIdx.x / NCHUNK;
  int chunk = blockIdx.x - rhalf * NCHUNK;
  __shared__ unsigned long long sl[32][128];  // 32 KB
  int tid = threadIdx.x;
  int q = tid & 31;  // quad: bins [4q..4q+3] within the chunk
  int s = tid >> 5;  // subslice 0..31
  int rc = R >> 1;   // copies per half (128 at R=256)
  int r0 = rhalf * rc + s;

  const unsigned* base = copies + chunk * 128 + q * 4;
  unsigned long long A0 = 0, A1 = 0, A2 = 0, A3 = 0;
  for (int k = 0; k < rc; k += 32) {
    uint4 v = *(const uint4*)(base + (size_t)(r0 + k) * NB);
    A0 += UNPACK(v.x);
    A1 += UNPACK(v.y);
    A2 += UNPACK(v.z);
    A3 += UNPACK(v.w);
  }
  sl[s][q * 4 + 0] = A0;
  sl[s][q * 4 + 1] = A1;
  sl[s][q * 4 + 2] = A2;
  sl[s][q * 4 + 3] = A3;
  __syncthreads();

  if (tid < 128) {
    unsigned long long t = 0;
#pragma unroll
    for (int i = 0; i < 32; ++i) t += sl[i][tid];
    part[(size_t)rhalf * NB + chunk * 128 + tid] = t;
  }
}

// ---------------------------------------------------------------------------
// Phase 3 (proven R18 scan; only the 2-half sum is new): 19 blocks x 512
// threads read part[2][NB] (L2-resident), sum the halves, run the 512-wide
// Hillis-Steele inclusive suffix scan + Lovasz J (loss_c = (1/BINS) *
// sum_{b>=1} J_b, (CP,CN) inclusive suffix counts at b, nPos = suffix at
// bin 0), and fuse the final mean via the proven spin-free ticket.
// ---------------------------------------------------------------------------
__global__ void __launch_bounds__(512) scan19_hist(
    const unsigned long long* __restrict__ part, float* __restrict__ partial,
    unsigned* __restrict__ counter, float* __restrict__ out) {
  int c = blockIdx.x;
  __shared__ unsigned long long binsA[BINS];  // 4 KB
  __shared__ float fsum[8];
  int tid = threadIdx.x;

  binsA[tid] = part[(c << 9) + tid] + part[NB + (c << 9) + tid];
  __syncthreads();

  // inclusive suffix scan over BINS entries (Hillis-Steele, 9 rounds)
  for (int off = 1; off < BINS; off <<= 1) {
    unsigned long long add = (tid + off < BINS) ? binsA[tid + off] : 0ull;
    __syncthreads();
    binsA[tid] += add;
    __syncthreads();
  }

  float nPos = (float)(unsigned)(binsA[0] >> 32);  // class total positives
  float acc = 0.f;
  if (tid >= 1) {
    unsigned long long suff = binsA[tid];
    float CP = (float)(unsigned)(suff >> 32);
    float CN = (float)(unsigned)(suff & 0xffffffffull);
    float uni = nPos + CN;
    if (uni > 0.f) acc = 1.0f - (nPos - CP) / uni;
  }

  // block reduce (fixed order) + ticket-fused final mean
  for (int off = 32; off > 0; off >>= 1) acc += __shfl_down(acc, off, 64);
  int lane = tid & 63, w = tid >> 6;
  if (lane == 0) fsum[w] = acc;
  __syncthreads();
  if (tid == 0) {
    float t = 0.f;
#pragma unroll
    for (int i = 0; i < 8; ++i) t += fsum[i];
    partial[c] = t;
    __threadfence();  // release: partial[c] visible before ticket
    unsigned tk = atomicAdd(counter, 1u);
    if (tk == NCLASS - 1) {  // all 18 others already released their partial
      __threadfence();       // acquire
      float m = 0.f;
#pragma unroll
      for (int i = 0; i < NCLASS; ++i)
        m += __hip_atomic_load(&partial[i], __ATOMIC_RELAXED,
                               __HIP_MEMORY_SCOPE_AGENT);
      out[0] = m * (1.0f / ((float)BINS * (float)NCLASS));
    }
  }
}

extern "C" void kernel_launch(void* const* d_in, const int* in_sizes, int n_in,
                              void* d_out, int out_size, void* d_ws,
                              size_t ws_size, hipStream_t stream) {
  const float* logits = (const float*)d_in[0];
  const int* labels = (const int*)d_in[1];
  float* out = (float*)d_out;

  const int P = in_sizes[1];  // 8*512*512 = 2,097,152

  // R = copy count = hist grid; 256 = 1 block/CU. Shrink if ws is tiny
  // (R/2 stays a multiple of 32 for fold_wide's subslice stride).
  int R = 256;
  while (R > 64 && (size_t)R * NB * 4 + (size_t)2 * NB * 8 + 4096 > ws_size)
    R >>= 1;
  // ppb multiple of 2048 keeps float2/int2 loads aligned. 8192 at R=256.
  int ppb = ((P + R - 1) / R + 2047) & ~2047;

  char* ws = (char*)d_ws;
  unsigned* copies = (unsigned*)ws;  // 10 MB
  unsigned long long* part =
      (unsigned long long*)(ws + (size_t)R * NB * 4);  // 2*NB u64 = 156 KB
  float* partial = (float*)(part + 2 * NB);
  unsigned* counter = (unsigned*)(partial + 32);

  size_t ldsBytes = (size_t)NREP * RSTRIDE * 4;  // ~152 KB -> 1 block/CU

  hist_pf<<<R, 1024, ldsBytes, stream>>>(logits, labels, copies, counter, P,
                                         ppb);
  fold_wide<<<2 * (NB / 128), 1024, 0, stream>>>(copies, part, R);
  scan19_hist<<<NCLASS, 512, 0, stream>>>(part, partial, counter, out);
}